// Round 8
// baseline (245.757 us; speedup 1.0000x reference)
//
#include <hip/hip_runtime.h>
#include <math.h>

#define GSZ 512
#define NSZ 256
#define NBATCH 8
#define MPTS 131072
#define PI_F 3.14159265358979f
#define BETA_F 13.8551004f
#define BETA2_F (BETA_F * BETA_F)
#define RSQ2 0.70710678f
// LDS pad: +1 float2 every 8 → strided radix-8 access conflict-reduced
#define PADIDX(i) ((i) + ((i) >> 3))

// ------------------------------------------------- per-batch grid barrier
// Generational sense barrier in __device__ globals: zero-initialized at
// module load; cnt returns to 0 after every episode and gen grows
// monotonically, so graph replays see a clean state (same work every call).
// 64 blocks per batch; with b = blockIdx&7 all participants share an XCD,
// so the atomics stay in one L2.
struct __align__(128) BatchBar { unsigned cnt; unsigned gen; unsigned pad[30]; };
__device__ BatchBar g_bar[NBATCH];

__device__ __forceinline__ void batch_sync(int b) {
    __syncthreads();                    // all waves' global writes drained (vmcnt)
    if (threadIdx.x == 0) {
        __threadfence();                // agent-scope release
        unsigned g = __hip_atomic_load(&g_bar[b].gen, __ATOMIC_RELAXED, __HIP_MEMORY_SCOPE_AGENT);
        unsigned a = __hip_atomic_fetch_add(&g_bar[b].cnt, 1u, __ATOMIC_ACQ_REL, __HIP_MEMORY_SCOPE_AGENT);
        if (a == 63u) {                 // last of this batch's 64 blocks
            __hip_atomic_store(&g_bar[b].cnt, 0u, __ATOMIC_RELAXED, __HIP_MEMORY_SCOPE_AGENT);
            __hip_atomic_fetch_add(&g_bar[b].gen, 1u, __ATOMIC_RELEASE, __HIP_MEMORY_SCOPE_AGENT);
        } else {
            while (__hip_atomic_load(&g_bar[b].gen, __ATOMIC_ACQUIRE, __HIP_MEMORY_SCOPE_AGENT) == g)
                __builtin_amdgcn_s_sleep(2);
        }
        __threadfence();                // acquire side
    }
    __syncthreads();
}

// ---------------------------------------------------------------- helpers

__device__ __forceinline__ float apod(int i) {
    float x = (float)(i - 128);
    float arg = PI_F * 6.0f * x * (1.0f / 512.0f);
    float t = BETA2_F - arg * arg;
    float st = sqrtf(t);
    return st / sinhf(st);
}

// Branchless Kaiser-Bessel weight (large-x asymptotic i0; central taps
// x>=13 err ~3e-5, edge-tap error ~4e-6 of center product).
__device__ __forceinline__ float kbw(float u) {
    float t = 1.0f - u * u * (1.0f / 9.0f);
    float x = BETA_F * sqrtf(fmaxf(t, 0.0f));
    float xc = fmaxf(x, 0.35f);
    float r = __builtin_amdgcn_rcpf(xc);
    float poly = 1.0f + r * (0.125f + r * 0.0703125f);
    float w = __expf(xc) * __builtin_amdgcn_rsqf(6.2831853f * xc) * poly;
    return (t > 0.0f) ? w : 0.0f;
}

// DPP quad_perm cross-lane (no DS pipe)
template<int CTRL>
__device__ __forceinline__ float qdpp(float v) {
    int r = __builtin_amdgcn_mov_dpp(__float_as_int(v), CTRL, 0xF, 0xF, true);
    return __int_as_float(r);
}

struct __align__(8) F4 { float x, y, z, w; };   // 2 float2 taps

__device__ __forceinline__ float2 cadd(float2 a, float2 b){ return make_float2(a.x+b.x, a.y+b.y); }
__device__ __forceinline__ float2 csub(float2 a, float2 b){ return make_float2(a.x-b.x, a.y-b.y); }
__device__ __forceinline__ float2 cmul(float2 a, float2 b){ return make_float2(a.x*b.x-a.y*b.y, a.x*b.y+a.y*b.x); }
__device__ __forceinline__ float2 mul_negi(float2 a){ return make_float2(a.y, -a.x); }
__device__ __forceinline__ float2 mul_posi(float2 a){ return make_float2(-a.y, a.x); }
__device__ __forceinline__ float2 mul_w81(float2 a){ return make_float2(RSQ2*(a.x+a.y), RSQ2*(a.y-a.x)); }
__device__ __forceinline__ float2 mul_w83(float2 a){ return make_float2(RSQ2*(a.y-a.x), -RSQ2*(a.x+a.y)); }

__device__ __forceinline__ void dft8_combine(float2 E0, float2 E1, float2 E2, float2 E3,
                                             float2 O0, float2 O1, float2 O2, float2 O3,
                                             float2* y) {
    float2 c1 = mul_w81(O1), c2 = mul_negi(O2), c3 = mul_w83(O3);
    y[0] = cadd(E0, O0); y[4] = csub(E0, O0);
    y[1] = cadd(E1, c1); y[5] = csub(E1, c1);
    y[2] = cadd(E2, c2); y[6] = csub(E2, c2);
    y[3] = cadd(E3, c3); y[7] = csub(E3, c3);
}

__device__ __forceinline__ void dft8(const float2* x, float2* y) {
    float2 a0=x[0], a1=x[2], a2=x[4], a3=x[6];
    float2 b0=x[1], b1=x[3], b2=x[5], b3=x[7];
    float2 ta0=cadd(a0,a2), ta1=csub(a0,a2), ta2=cadd(a1,a3), ta3=csub(a1,a3);
    float2 E0=cadd(ta0,ta2), E2=csub(ta0,ta2);
    float2 E1=cadd(ta1, mul_negi(ta3)), E3=cadd(ta1, mul_posi(ta3));
    float2 tb0=cadd(b0,b2), tb1=csub(b0,b2), tb2=cadd(b1,b3), tb3=csub(b1,b3);
    float2 O0=cadd(tb0,tb2), O2=csub(tb0,tb2);
    float2 O1=cadd(tb1, mul_negi(tb3)), O3=cadd(tb1, mul_posi(tb3));
    dft8_combine(E0,E1,E2,E3,O0,O1,O2,O3,y);
}

__device__ __forceinline__ void dft8_pruned(float2 x0, float2 x1, float2 x6, float2 x7, float2* y) {
    float2 E0 = cadd(x0, x6), E2 = csub(x0, x6);
    float2 E1 = cadd(x0, mul_posi(x6)), E3 = cadd(x0, mul_negi(x6));
    float2 O0 = cadd(x1, x7), O2 = csub(x1, x7);
    float2 O1 = cadd(x1, mul_posi(x7)), O3 = cadd(x1, mul_negi(x7));
    dft8_combine(E0,E1,E2,E3,O0,O1,O2,O3,y);
}

template<int S>
__device__ __forceinline__ void twiddle8(int t, float2* y) {
    if (S < 2) {
        int j = (S == 0) ? t : (t >> 3);
        const float scale = (S == 0) ? (-2.0f*PI_F/512.0f) : (-2.0f*PI_F/64.0f);
        float theta = scale * (float)j;
        float sn, cs;
        __sincosf(theta, &sn, &cs);              // sin FIRST, cos second
        float2 w = make_float2(cs, sn), wq = w;
        y[1] = cmul(y[1], wq);
        #pragma unroll
        for (int q = 2; q < 8; ++q) { wq = cmul(wq, w); y[q] = cmul(y[q], wq); }
    }
}

// ---------------------------------------------------------------- fused
// 512 blocks x 256 threads, all co-resident (2 blocks/CU; LDS 37 KB -> 4/CU
// cap; launch_bounds caps VGPR at 128). b = blk&7 pins each batch's whole
// pipeline (row FFT -> col FFT -> gather) to one XCD; per-batch barriers let
// batches pipeline independently.
__global__ __launch_bounds__(256, 2) void nufft_fused(const float* __restrict__ image,
                                                      const float* __restrict__ ktraj,
                                                      const float* __restrict__ dcf,
                                                      float2* __restrict__ T,
                                                      float2* __restrict__ kgrid,
                                                      float* __restrict__ out) {
    __shared__ float2 smem[8 * 578];
    int tid = threadIdx.x;
    int blk = blockIdx.x;
    int b = blk & 7;
    int g = blk >> 3;                               // 0..63

    // ================= phase 1: row FFT (4 rows/block, compact 256-row T)
    {
        int r = tid >> 6, t = tid & 63;
        int rp = (g << 2) + r;                      // compact row 0..255
        int y = (rp < 128) ? rp : (rp + 256);
        int iy = (y < 128) ? (y + 128) : (y - 384);
        float ay = apod(iy);
        const float* irow = image + ((size_t)(b * NSZ + iy)) * NSZ;

        float2 y8[8];
        {
            int ix0 = t + 128, ix1 = t + 192, ix6 = t, ix7 = t + 64;
            float2 x0 = make_float2(irow[ix0] * ay * apod(ix0), 0.f);
            float2 x1 = make_float2(irow[ix1] * ay * apod(ix1), 0.f);
            float2 x6 = make_float2(irow[ix6] * ay * apod(ix6), 0.f);
            float2 x7 = make_float2(irow[ix7] * ay * apod(ix7), 0.f);
            dft8_pruned(x0, x1, x6, x7, y8);
            twiddle8<0>(t, y8);
        }
        float2* A  = smem + r * 578;
        float2* Bf = smem + (r + 4) * 578;
        #pragma unroll
        for (int q = 0; q < 8; ++q) A[PADIDX((t << 3) + q)] = y8[q];
        __syncthreads();
        {
            float2 x[8];
            #pragma unroll
            for (int p = 0; p < 8; ++p) x[p] = A[PADIDX(t + (p << 6))];
            dft8(x, y8);
            twiddle8<1>(t, y8);
            int j = t >> 3, k = t & 7, base = k + (j << 6);
            #pragma unroll
            for (int q = 0; q < 8; ++q) Bf[PADIDX(base + (q << 3))] = y8[q];
        }
        __syncthreads();
        {
            float2 x[8];
            #pragma unroll
            for (int p = 0; p < 8; ++p) x[p] = Bf[PADIDX(t + (p << 6))];
            dft8(x, y8);
            float2* Trow = T + (((size_t)(b << 8) + rp) << 9);
            #pragma unroll
            for (int q = 0; q < 8; ++q) Trow[t + (q << 6)] = y8[q];
        }
    }

    batch_sync(b);   // batch b's T complete

    // ================= phase 2: column FFT (8 cols/block)
    {
        int colbase = g << 3;                       // 0..504 step 8
        const float2* Tb = T + ((size_t)b << 17);   // 256*512 per batch
        float2* Kb = kgrid + ((size_t)b << 18);
        float2* B0 = smem;                          // 8 column buffers of 578

        {
            int c = tid & 7, r0 = tid >> 3;         // r0 0..31
            #pragma unroll
            for (int k = 0; k < 8; ++k) {
                int rr = r0 + (k << 5);
                B0[c * 578 + PADIDX(rr)] = Tb[((size_t)rr << 9) + colbase + c];
            }
        }
        __syncthreads();
        int t = tid & 63;
        int c0 = tid >> 6;                          // cols c0 and c0+4
        float2* Ba = B0 + c0 * 578;
        float2* Bb = B0 + (c0 + 4) * 578;
        float2 ya[8], yb[8];
        {
            float2 a0 = Ba[PADIDX(t)],     a1 = Ba[PADIDX(t + 64)];
            float2 a6 = Ba[PADIDX(t + 128)], a7 = Ba[PADIDX(t + 192)];
            float2 b0 = Bb[PADIDX(t)],     b1 = Bb[PADIDX(t + 64)];
            float2 b6 = Bb[PADIDX(t + 128)], b7 = Bb[PADIDX(t + 192)];
            dft8_pruned(a0, a1, a6, a7, ya); twiddle8<0>(t, ya);
            dft8_pruned(b0, b1, b6, b7, yb); twiddle8<0>(t, yb);
        }
        __syncthreads();
        #pragma unroll
        for (int q = 0; q < 8; ++q) {
            Ba[PADIDX((t << 3) + q)] = ya[q];
            Bb[PADIDX((t << 3) + q)] = yb[q];
        }
        __syncthreads();
        {
            float2 xa[8], xb[8];
            #pragma unroll
            for (int p = 0; p < 8; ++p) { xa[p] = Ba[PADIDX(t + (p << 6))]; xb[p] = Bb[PADIDX(t + (p << 6))]; }
            dft8(xa, ya); twiddle8<1>(t, ya);
            dft8(xb, yb); twiddle8<1>(t, yb);
        }
        __syncthreads();
        {
            int j = t >> 3, k = t & 7, base = k + (j << 6);
            #pragma unroll
            for (int q = 0; q < 8; ++q) {
                Ba[PADIDX(base + (q << 3))] = ya[q];
                Bb[PADIDX(base + (q << 3))] = yb[q];
            }
        }
        __syncthreads();
        {
            float2 xa[8], xb[8];
            #pragma unroll
            for (int p = 0; p < 8; ++p) { xa[p] = Ba[PADIDX(t + (p << 6))]; xb[p] = Bb[PADIDX(t + (p << 6))]; }
            dft8(xa, ya);
            dft8(xb, yb);
        }
        __syncthreads();
        #pragma unroll
        for (int q = 0; q < 8; ++q) {
            Ba[PADIDX(t + (q << 6))] = ya[q];
            Bb[PADIDX(t + (q << 6))] = yb[q];
        }
        __syncthreads();
        {
            int c = tid & 7, r0 = tid >> 3;
            #pragma unroll
            for (int k = 0; k < 16; ++k) {
                int rr = r0 + (k << 5);
                Kb[((size_t)rr << 9) + colbase + c] = B0[c * 578 + PADIDX(rr)];
            }
        }
    }

    batch_sync(b);   // batch b's kgrid complete

    // ================= phase 3: quad-cooperative KB gather (2048 pts/block)
    {
        int j = tid & 3;                      // lane within quad
        int q = tid >> 2;                     // quad in block 0..63

        const float SCALE = (float)GSZ / (2.0f * PI_F);
        const float2* Kb = kgrid + ((size_t)b << 18);
        const float* kt1 = ktraj + ((size_t)(b * 2)) * MPTS;
        const float* kt2 = kt1 + MPTS;
        const float* dcfb = dcf + ((size_t)b << 17);
        float* out_re = out + ((size_t)b << 17);
        float* out_im = out_re + (size_t)NBATCH * MPTS;

        int m0 = (g << 11) + q;               // block covers 2048 points
        #pragma unroll 2
        for (int it = 0; it < 32; ++it) {
            int m = m0 + (it << 6);
            float tm1 = kt1[m] * SCALE;
            float tm2 = kt2[m] * SCALE;
            float f1 = floorf(tm1), f2 = floorf(tm2);
            int if1 = (int)f1, if2 = (int)f2;
            int e0 = (if2 - 2) & ~1;          // even base col

            float u2 = tm2 - (float)(e0 + 2 * j);
            float w2a = kbw(u2);
            float w2b = kbw(u2 - 1.0f);
            int cpair = (e0 + 2 * j) & 511;   // even → pair never wraps mid

            float fr1 = tm1 - f1;
            float w1A = kbw(fr1 - (float)(j - 2));
            float w1B = kbw(fr1 - (float)(j + 2));

            float c0re = 0.f, c0im = 0.f, c1re = 0.f, c1im = 0.f;
            #define KB_ROW(a, W, CTRL)                                            \
            {                                                                     \
                float w1a = qdpp<CTRL>(W);                                        \
                int rowb = (if1 + (a) - 2) & 511;                                 \
                F4 v = *reinterpret_cast<const F4*>(Kb + ((size_t)rowb << 9) + cpair); \
                c0re = fmaf(w1a, v.x, c0re); c0im = fmaf(w1a, v.y, c0im);         \
                c1re = fmaf(w1a, v.z, c1re); c1im = fmaf(w1a, v.w, c1im);         \
            }
            KB_ROW(0, w1A, 0x00)
            KB_ROW(1, w1A, 0x55)
            KB_ROW(2, w1A, 0xAA)
            KB_ROW(3, w1A, 0xFF)
            KB_ROW(4, w1B, 0x00)
            KB_ROW(5, w1B, 0x55)
            #undef KB_ROW

            float p_re = fmaf(w2a, c0re, w2b * c1re);
            float p_im = fmaf(w2a, c0im, w2b * c1im);
            p_re += qdpp<0xB1>(p_re);  p_re += qdpp<0x4E>(p_re);
            p_im += qdpp<0xB1>(p_im);  p_im += qdpp<0x4E>(p_im);

            float dd = dcfb[m];
            if (j == 0) out_re[m] = p_re * dd;
            if (j == 1) out_im[m] = p_im * dd;
        }
    }
}

// ---------------------------------------------------------------- launch

extern "C" void kernel_launch(void* const* d_in, const int* in_sizes, int n_in,
                              void* d_out, int out_size, void* d_ws, size_t ws_size,
                              hipStream_t stream) {
    const float* image = (const float*)d_in[0];   // (8,256,256) f32
    const float* ktraj = (const float*)d_in[1];   // (8,2,131072) f32
    const float* dcf   = (const float*)d_in[2];   // (8,131072) f32
    float* out = (float*)d_out;                   // (2,8,131072) f32

    float2* T     = (float2*)d_ws;                        // 8*256*512 c64 = 8.4 MB
    float2* kgrid = T + (size_t)NBATCH * 256 * GSZ;       // 8*512*512 c64 = 16.8 MB

    nufft_fused<<<NBATCH * 64, 256, 0, stream>>>(image, ktraj, dcf, T, kgrid, out);
}

// Round 9
// 130.731 us; speedup vs baseline: 1.8799x; 1.8799x over previous
//
#include <hip/hip_runtime.h>
#include <math.h>

#define GSZ 512
#define NSZ 256
#define NBATCH 8
#define MPTS 131072
#define PI_F 3.14159265358979f
#define BETA_F 13.8551004f
#define BETA2_F (BETA_F * BETA_F)
#define RSQ2 0.70710678f
// LDS pad: +1 float2 every 8 → strided radix-8 access conflict-reduced
#define PADIDX(i) ((i) + ((i) >> 3))

// ---------------------------------------------------------------- helpers

__device__ __forceinline__ float apod(int i) {
    float x = (float)(i - 128);
    float arg = PI_F * 6.0f * x * (1.0f / 512.0f);
    float t = BETA2_F - arg * arg;
    float st = sqrtf(t);
    return st / sinhf(st);
}

// Branchless Kaiser-Bessel weight, large-x asymptotic i0 with the 1/x
// correction folded into powers of R = rsq(x): only 3 transcendentals
// (sqrt, rsq, exp) — the rcp is gone.
//   w = e^x * R * (1/sqrt(2pi) + c1*R^2 + c2*R^4),  R = x^(-1/2)
__device__ __forceinline__ float kbw(float u) {
    float t = 1.0f - u * u * (1.0f / 9.0f);
    float x = BETA_F * sqrtf(fmaxf(t, 0.0f));
    float xc = fmaxf(x, 0.35f);
    float R = __builtin_amdgcn_rsqf(xc);
    float R2 = R * R;
    float q = R * (0.39894228f + R2 * (0.04986779f + R2 * 0.02804702f));
    float w = __expf(xc) * q;
    return (t > 0.0f) ? w : 0.0f;
}

// DPP quad_perm cross-lane (no DS pipe)
template<int CTRL>
__device__ __forceinline__ float qdpp(float v) {
    int r = __builtin_amdgcn_mov_dpp(__float_as_int(v), CTRL, 0xF, 0xF, true);
    return __int_as_float(r);
}

struct __align__(8) F4 { float x, y, z, w; };   // 2 float2 taps

__device__ __forceinline__ float2 cadd(float2 a, float2 b){ return make_float2(a.x+b.x, a.y+b.y); }
__device__ __forceinline__ float2 csub(float2 a, float2 b){ return make_float2(a.x-b.x, a.y-b.y); }
__device__ __forceinline__ float2 cmul(float2 a, float2 b){ return make_float2(a.x*b.x-a.y*b.y, a.x*b.y+a.y*b.x); }
__device__ __forceinline__ float2 mul_negi(float2 a){ return make_float2(a.y, -a.x); }
__device__ __forceinline__ float2 mul_posi(float2 a){ return make_float2(-a.y, a.x); }
__device__ __forceinline__ float2 mul_w81(float2 a){ return make_float2(RSQ2*(a.x+a.y), RSQ2*(a.y-a.x)); }
__device__ __forceinline__ float2 mul_w83(float2 a){ return make_float2(RSQ2*(a.y-a.x), -RSQ2*(a.x+a.y)); }

__device__ __forceinline__ void dft8_combine(float2 E0, float2 E1, float2 E2, float2 E3,
                                             float2 O0, float2 O1, float2 O2, float2 O3,
                                             float2* y) {
    float2 c1 = mul_w81(O1), c2 = mul_negi(O2), c3 = mul_w83(O3);
    y[0] = cadd(E0, O0); y[4] = csub(E0, O0);
    y[1] = cadd(E1, c1); y[5] = csub(E1, c1);
    y[2] = cadd(E2, c2); y[6] = csub(E2, c2);
    y[3] = cadd(E3, c3); y[7] = csub(E3, c3);
}

__device__ __forceinline__ void dft8(const float2* x, float2* y) {
    float2 a0=x[0], a1=x[2], a2=x[4], a3=x[6];
    float2 b0=x[1], b1=x[3], b2=x[5], b3=x[7];
    float2 ta0=cadd(a0,a2), ta1=csub(a0,a2), ta2=cadd(a1,a3), ta3=csub(a1,a3);
    float2 E0=cadd(ta0,ta2), E2=csub(ta0,ta2);
    float2 E1=cadd(ta1, mul_negi(ta3)), E3=cadd(ta1, mul_posi(ta3));
    float2 tb0=cadd(b0,b2), tb1=csub(b0,b2), tb2=cadd(b1,b3), tb3=csub(b1,b3);
    float2 O0=cadd(tb0,tb2), O2=csub(tb0,tb2);
    float2 O1=cadd(tb1, mul_negi(tb3)), O3=cadd(tb1, mul_posi(tb3));
    dft8_combine(E0,E1,E2,E3,O0,O1,O2,O3,y);
}

__device__ __forceinline__ void dft8_pruned(float2 x0, float2 x1, float2 x6, float2 x7, float2* y) {
    float2 E0 = cadd(x0, x6), E2 = csub(x0, x6);
    float2 E1 = cadd(x0, mul_posi(x6)), E3 = cadd(x0, mul_negi(x6));
    float2 O0 = cadd(x1, x7), O2 = csub(x1, x7);
    float2 O1 = cadd(x1, mul_posi(x7)), O3 = cadd(x1, mul_negi(x7));
    dft8_combine(E0,E1,E2,E3,O0,O1,O2,O3,y);
}

template<int S>
__device__ __forceinline__ void twiddle8(int t, float2* y) {
    if (S < 2) {
        int j = (S == 0) ? t : (t >> 3);
        const float scale = (S == 0) ? (-2.0f*PI_F/512.0f) : (-2.0f*PI_F/64.0f);
        float theta = scale * (float)j;
        float sn, cs;
        __sincosf(theta, &sn, &cs);              // sin FIRST, cos second
        float2 w = make_float2(cs, sn), wq = w;
        y[1] = cmul(y[1], wq);
        #pragma unroll
        for (int q = 2; q < 8; ++q) { wq = cmul(wq, w); y[q] = cmul(y[q], wq); }
    }
}

// ---------------------------------------------------------------- pass 1
// Batch-pair packed row FFT: z = img_{2p} + i*img_{2p+1} (both real, same
// zero support) -> 4 combined grids instead of 8. 2 rows/block, 128 thr.
// T compact: pair p, 256 nonzero rows of 512 cols.
__global__ __launch_bounds__(128) void pass1_rowfft(const float* __restrict__ image,
                                                    float2* __restrict__ T) {
    __shared__ float2 sm[2][2][578];
    int tid = threadIdx.x;
    int r = tid >> 6, t = tid & 63;                 // r in {0,1}
    int blk = blockIdx.x;
    int p = blk & 3;                                // batch pair 0..3
    int g = blk >> 2;                               // 0..127
    int rp = (g << 1) + r;                          // compact row 0..255
    int y = (rp < 128) ? rp : (rp + 256);
    int iy = (y < 128) ? (y + 128) : (y - 384);
    float ay = apod(iy);
    const float* irow0 = image + ((size_t)((2 * p)     * NSZ + iy)) * NSZ;
    const float* irow1 = image + ((size_t)((2 * p + 1) * NSZ + iy)) * NSZ;

    float2 y8[8];
    { // stage 0 (pruned): packed complex input z = img0 + i*img1
        int ix0 = t + 128, ix1 = t + 192, ix6 = t, ix7 = t + 64;
        float w0 = ay * apod(ix0), w1 = ay * apod(ix1);
        float w6 = ay * apod(ix6), w7 = ay * apod(ix7);
        float2 x0 = make_float2(irow0[ix0] * w0, irow1[ix0] * w0);
        float2 x1 = make_float2(irow0[ix1] * w1, irow1[ix1] * w1);
        float2 x6 = make_float2(irow0[ix6] * w6, irow1[ix6] * w6);
        float2 x7 = make_float2(irow0[ix7] * w7, irow1[ix7] * w7);
        dft8_pruned(x0, x1, x6, x7, y8);
        twiddle8<0>(t, y8);
    }
    float2* A  = sm[0][r];
    float2* Bf = sm[1][r];
    #pragma unroll
    for (int q = 0; q < 8; ++q) A[PADIDX((t << 3) + q)] = y8[q];
    __syncthreads();
    {
        float2 x[8];
        #pragma unroll
        for (int pp = 0; pp < 8; ++pp) x[pp] = A[PADIDX(t + (pp << 6))];
        dft8(x, y8);
        twiddle8<1>(t, y8);
        int j = t >> 3, k = t & 7, base = k + (j << 6);
        #pragma unroll
        for (int q = 0; q < 8; ++q) Bf[PADIDX(base + (q << 3))] = y8[q];
    }
    __syncthreads();
    {
        float2 x[8];
        #pragma unroll
        for (int pp = 0; pp < 8; ++pp) x[pp] = Bf[PADIDX(t + (pp << 6))];
        dft8(x, y8);
        float2* Trow = T + (((size_t)(p << 8) + rp) << 9);
        #pragma unroll
        for (int q = 0; q < 8; ++q) Trow[t + (q << 6)] = y8[q];
    }
}

// ---------------------------------------------------------------- pass 2
// Batch-pair packed column FFT + Hermitian unpack. Block owns a MIRRORED
// col set so conj(Z[-k1,-k2]) is block-local: g>0 -> {4g..4g+3} u
// {509-4g..512-4g}; g==0 -> {0,1,2,3,509,510,511,256}. After the col FFT,
// K_b0 = (Z + conj(Zm))/2, K_b1 = -i(Z - conj(Zm))/2 with Zm = mirror
// slot at row (512-k1)&511. Stores the full kgrid for both batches.
__global__ __launch_bounds__(256) void pass2_colfft(const float2* __restrict__ T,
                                                    float2* __restrict__ kgrid) {
    __shared__ float2 B[8][578];
    int tid = threadIdx.x;
    int blk = blockIdx.x;
    int p = blk & 3;                                // batch pair
    int g = blk >> 2;                               // 0..63 col group
    const float2* Tb = T + ((size_t)p << 17);       // 256*512 per pair
    float2* Kb0 = kgrid + ((size_t)(2 * p) << 18);
    float2* Kb1 = Kb0 + ((size_t)1 << 18);

    // global column for LDS slot c (block-uniform g, per-lane c)
    #define COLG(c) ((g > 0) ? (((c) < 4) ? ((g << 2) + (c)) : (505 - (g << 2) + (c))) \
                             : (((c) < 4) ? (c) : (((c) == 7) ? 256 : (505 + (c)))))

    { // load: 256 compact rows x 8 slot-cols
        int c = tid & 7, r0 = tid >> 3;             // r0 0..31
        int colg = COLG(c);
        #pragma unroll
        for (int k = 0; k < 8; ++k) {
            int rr = r0 + (k << 5);
            B[c][PADIDX(rr)] = Tb[((size_t)rr << 9) + colg];
        }
    }
    __syncthreads();
    int t = tid & 63;
    int c0 = tid >> 6;                              // slots c0 and c0+4
    float2* Ba = B[c0];
    float2* Bb = B[c0 + 4];
    float2 ya[8], yb[8];
    { // stage 0 (pruned): compact rows {t, t+64, t+128, t+192}
        float2 a0 = Ba[PADIDX(t)],       a1 = Ba[PADIDX(t + 64)];
        float2 a6 = Ba[PADIDX(t + 128)], a7 = Ba[PADIDX(t + 192)];
        float2 b0 = Bb[PADIDX(t)],       b1 = Bb[PADIDX(t + 64)];
        float2 b6 = Bb[PADIDX(t + 128)], b7 = Bb[PADIDX(t + 192)];
        dft8_pruned(a0, a1, a6, a7, ya); twiddle8<0>(t, ya);
        dft8_pruned(b0, b1, b6, b7, yb); twiddle8<0>(t, yb);
    }
    __syncthreads();
    #pragma unroll
    for (int q = 0; q < 8; ++q) {
        Ba[PADIDX((t << 3) + q)] = ya[q];
        Bb[PADIDX((t << 3) + q)] = yb[q];
    }
    __syncthreads();
    {
        float2 xa[8], xb[8];
        #pragma unroll
        for (int pp = 0; pp < 8; ++pp) { xa[pp] = Ba[PADIDX(t + (pp << 6))]; xb[pp] = Bb[PADIDX(t + (pp << 6))]; }
        dft8(xa, ya); twiddle8<1>(t, ya);
        dft8(xb, yb); twiddle8<1>(t, yb);
    }
    __syncthreads();
    {
        int j = t >> 3, k = t & 7, base = k + (j << 6);
        #pragma unroll
        for (int q = 0; q < 8; ++q) {
            Ba[PADIDX(base + (q << 3))] = ya[q];
            Bb[PADIDX(base + (q << 3))] = yb[q];
        }
    }
    __syncthreads();
    {
        float2 xa[8], xb[8];
        #pragma unroll
        for (int pp = 0; pp < 8; ++pp) { xa[pp] = Ba[PADIDX(t + (pp << 6))]; xb[pp] = Bb[PADIDX(t + (pp << 6))]; }
        dft8(xa, ya);
        dft8(xb, yb);
    }
    __syncthreads();
    #pragma unroll
    for (int q = 0; q < 8; ++q) {
        Ba[PADIDX(t + (q << 6))] = ya[q];
        Bb[PADIDX(t + (q << 6))] = yb[q];
    }
    __syncthreads();
    { // unpack + store: K0/K1 for all 8 cols, 512 rows
        int c = tid & 7, r0 = tid >> 3;
        int colg = COLG(c);
        // mirror slot: g>0 -> 7-c ; g==0 -> {0->0, 7->7, else 7-c}
        int mc = 7 - c;
        if (g == 0) { if (c == 0) mc = 0; else if (c == 7) mc = 7; }
        #pragma unroll
        for (int k = 0; k < 16; ++k) {
            int rr = r0 + (k << 5);
            int mr = (512 - rr) & 511;
            float2 Z = B[c][PADIDX(rr)];
            float2 M = B[mc][PADIDX(mr)];
            float2 K0 = make_float2(0.5f * (Z.x + M.x), 0.5f * (Z.y - M.y));
            float2 K1 = make_float2(0.5f * (Z.y + M.y), 0.5f * (M.x - Z.x));
            size_t off = ((size_t)rr << 9) + colg;
            Kb0[off] = K0;
            Kb1[off] = K1;
        }
    }
    #undef COLG
}

// ---------------------------------------------------------------- pass 3
// Quad-cooperative KB gather (r7 structure): 4 lanes/point, DPP-only
// cross-lane, even col-pair per lane (one 16B load per row). b = blk&7
// keeps each batch's 2 MB grid L2-resident on one XCD.
__global__ __launch_bounds__(256) void interp_kb(const float* __restrict__ ktraj,
                                                 const float* __restrict__ dcf,
                                                 const float2* __restrict__ kgrid,
                                                 float* __restrict__ out) {
    int tid = threadIdx.x;
    int blk = blockIdx.x;
    int b = blk & 7;                          // XCD affinity
    int gb = blk >> 3;                        // 0..255
    int j = tid & 3;                          // lane within quad
    int q = tid >> 2;                         // quad in block 0..63

    const float SCALE = (float)GSZ / (2.0f * PI_F);
    const float2* Kb = kgrid + ((size_t)b << 18);
    const float* kt1 = ktraj + ((size_t)(b * 2)) * MPTS;
    const float* kt2 = kt1 + MPTS;
    const float* dcfb = dcf + ((size_t)b << 17);
    float* out_re = out + ((size_t)b << 17);
    float* out_im = out_re + (size_t)NBATCH * MPTS;

    int m0 = (gb << 9) + q;                   // block covers 512 points
    #pragma unroll 2
    for (int it = 0; it < 8; ++it) {
        int m = m0 + (it << 6);
        float tm1 = kt1[m] * SCALE;
        float tm2 = kt2[m] * SCALE;
        float f1 = floorf(tm1), f2 = floorf(tm2);
        int if1 = (int)f1, if2 = (int)f2;
        int e0 = (if2 - 2) & ~1;              // even base col

        float u2 = tm2 - (float)(e0 + 2 * j);
        float w2a = kbw(u2);
        float w2b = kbw(u2 - 1.0f);
        int cpair = (e0 + 2 * j) & 511;       // even → pair never wraps mid

        float fr1 = tm1 - f1;
        float w1A = kbw(fr1 - (float)(j - 2));
        float w1B = kbw(fr1 - (float)(j + 2));

        float c0re = 0.f, c0im = 0.f, c1re = 0.f, c1im = 0.f;
        #define KB_ROW(a, W, CTRL)                                            \
        {                                                                     \
            float w1a = qdpp<CTRL>(W);                                        \
            int rowb = (if1 + (a) - 2) & 511;                                 \
            F4 v = *reinterpret_cast<const F4*>(Kb + ((size_t)rowb << 9) + cpair); \
            c0re = fmaf(w1a, v.x, c0re); c0im = fmaf(w1a, v.y, c0im);         \
            c1re = fmaf(w1a, v.z, c1re); c1im = fmaf(w1a, v.w, c1im);         \
        }
        KB_ROW(0, w1A, 0x00)
        KB_ROW(1, w1A, 0x55)
        KB_ROW(2, w1A, 0xAA)
        KB_ROW(3, w1A, 0xFF)
        KB_ROW(4, w1B, 0x00)
        KB_ROW(5, w1B, 0x55)
        #undef KB_ROW

        float p_re = fmaf(w2a, c0re, w2b * c1re);
        float p_im = fmaf(w2a, c0im, w2b * c1im);
        p_re += qdpp<0xB1>(p_re);  p_re += qdpp<0x4E>(p_re);
        p_im += qdpp<0xB1>(p_im);  p_im += qdpp<0x4E>(p_im);

        float dd = dcfb[m];
        if (j == 0) out_re[m] = p_re * dd;
        if (j == 1) out_im[m] = p_im * dd;
    }
}

// ---------------------------------------------------------------- launch

extern "C" void kernel_launch(void* const* d_in, const int* in_sizes, int n_in,
                              void* d_out, int out_size, void* d_ws, size_t ws_size,
                              hipStream_t stream) {
    const float* image = (const float*)d_in[0];   // (8,256,256) f32
    const float* ktraj = (const float*)d_in[1];   // (8,2,131072) f32
    const float* dcf   = (const float*)d_in[2];   // (8,131072) f32
    float* out = (float*)d_out;                   // (2,8,131072) f32

    float2* T     = (float2*)d_ws;                        // 4 pairs *256*512 c64 = 4.2 MB
    float2* kgrid = T + (size_t)4 * 256 * GSZ;            // 8*512*512 c64 = 16.8 MB

    pass1_rowfft<<<512, 128, 0, stream>>>(image, T);      // 4 pairs * 256 rows / 2 per block
    pass2_colfft<<<256, 256, 0, stream>>>(T, kgrid);      // 4 pairs * 512 cols / 8 per block
    interp_kb<<<NBATCH * 256, 256, 0, stream>>>(ktraj, dcf, kgrid, out);
}

// Round 10
// 127.859 us; speedup vs baseline: 1.9221x; 1.0225x over previous
//
#include <hip/hip_runtime.h>
#include <math.h>

#define GSZ 512
#define NSZ 256
#define NBATCH 8
#define MPTS 131072
#define PI_F 3.14159265358979f
#define BETA_F 13.8551004f
#define BETA2_F (BETA_F * BETA_F)
#define RSQ2 0.70710678f
// LDS pad: +1 float2 every 8 → strided radix-8 access conflict-reduced
#define PADIDX(i) ((i) + ((i) >> 3))

// ---------------------------------------------------------------- helpers

__device__ __forceinline__ float apod(int i) {
    float x = (float)(i - 128);
    float arg = PI_F * 6.0f * x * (1.0f / 512.0f);
    float t = BETA2_F - arg * arg;
    float st = sqrtf(t);
    return st / sinhf(st);
}

// Branchless Kaiser-Bessel weight, large-x asymptotic i0 (3 transcendentals).
__device__ __forceinline__ float kbw(float u) {
    float t = 1.0f - u * u * (1.0f / 9.0f);
    float x = BETA_F * sqrtf(fmaxf(t, 0.0f));
    float xc = fmaxf(x, 0.35f);
    float R = __builtin_amdgcn_rsqf(xc);
    float R2 = R * R;
    float q = R * (0.39894228f + R2 * (0.04986779f + R2 * 0.02804702f));
    float w = __expf(xc) * q;
    return (t > 0.0f) ? w : 0.0f;
}

// DPP quad_perm cross-lane (no DS pipe)
template<int CTRL>
__device__ __forceinline__ float qdpp(float v) {
    int r = __builtin_amdgcn_mov_dpp(__float_as_int(v), CTRL, 0xF, 0xF, true);
    return __int_as_float(r);
}

struct __align__(8) F4 { float x, y, z, w; };   // 2 float2 taps

__device__ __forceinline__ float2 cadd(float2 a, float2 b){ return make_float2(a.x+b.x, a.y+b.y); }
__device__ __forceinline__ float2 csub(float2 a, float2 b){ return make_float2(a.x-b.x, a.y-b.y); }
__device__ __forceinline__ float2 cmul(float2 a, float2 b){ return make_float2(a.x*b.x-a.y*b.y, a.x*b.y+a.y*b.x); }
__device__ __forceinline__ float2 mul_negi(float2 a){ return make_float2(a.y, -a.x); }
__device__ __forceinline__ float2 mul_posi(float2 a){ return make_float2(-a.y, a.x); }
__device__ __forceinline__ float2 mul_w81(float2 a){ return make_float2(RSQ2*(a.x+a.y), RSQ2*(a.y-a.x)); }
__device__ __forceinline__ float2 mul_w83(float2 a){ return make_float2(RSQ2*(a.y-a.x), -RSQ2*(a.x+a.y)); }

__device__ __forceinline__ void dft8_combine(float2 E0, float2 E1, float2 E2, float2 E3,
                                             float2 O0, float2 O1, float2 O2, float2 O3,
                                             float2* y) {
    float2 c1 = mul_w81(O1), c2 = mul_negi(O2), c3 = mul_w83(O3);
    y[0] = cadd(E0, O0); y[4] = csub(E0, O0);
    y[1] = cadd(E1, c1); y[5] = csub(E1, c1);
    y[2] = cadd(E2, c2); y[6] = csub(E2, c2);
    y[3] = cadd(E3, c3); y[7] = csub(E3, c3);
}

__device__ __forceinline__ void dft8(const float2* x, float2* y) {
    float2 a0=x[0], a1=x[2], a2=x[4], a3=x[6];
    float2 b0=x[1], b1=x[3], b2=x[5], b3=x[7];
    float2 ta0=cadd(a0,a2), ta1=csub(a0,a2), ta2=cadd(a1,a3), ta3=csub(a1,a3);
    float2 E0=cadd(ta0,ta2), E2=csub(ta0,ta2);
    float2 E1=cadd(ta1, mul_negi(ta3)), E3=cadd(ta1, mul_posi(ta3));
    float2 tb0=cadd(b0,b2), tb1=csub(b0,b2), tb2=cadd(b1,b3), tb3=csub(b1,b3);
    float2 O0=cadd(tb0,tb2), O2=csub(tb0,tb2);
    float2 O1=cadd(tb1, mul_negi(tb3)), O3=cadd(tb1, mul_posi(tb3));
    dft8_combine(E0,E1,E2,E3,O0,O1,O2,O3,y);
}

__device__ __forceinline__ void dft8_pruned(float2 x0, float2 x1, float2 x6, float2 x7, float2* y) {
    float2 E0 = cadd(x0, x6), E2 = csub(x0, x6);
    float2 E1 = cadd(x0, mul_posi(x6)), E3 = cadd(x0, mul_negi(x6));
    float2 O0 = cadd(x1, x7), O2 = csub(x1, x7);
    float2 O1 = cadd(x1, mul_posi(x7)), O3 = cadd(x1, mul_negi(x7));
    dft8_combine(E0,E1,E2,E3,O0,O1,O2,O3,y);
}

template<int S>
__device__ __forceinline__ void twiddle8(int t, float2* y) {
    if (S < 2) {
        int j = (S == 0) ? t : (t >> 3);
        const float scale = (S == 0) ? (-2.0f*PI_F/512.0f) : (-2.0f*PI_F/64.0f);
        float theta = scale * (float)j;
        float sn, cs;
        __sincosf(theta, &sn, &cs);              // sin FIRST, cos second
        float2 w = make_float2(cs, sn), wq = w;
        y[1] = cmul(y[1], wq);
        #pragma unroll
        for (int q = 2; q < 8; ++q) { wq = cmul(wq, w); y[q] = cmul(y[q], wq); }
    }
}

// ---------------------------------------------------------------- pass 1
// Batch-pair packed row FFT (r9): z = img_{2p} + i*img_{2p+1}. 2 rows/block.
__global__ __launch_bounds__(128) void pass1_rowfft(const float* __restrict__ image,
                                                    float2* __restrict__ T) {
    __shared__ float2 sm[2][2][578];
    int tid = threadIdx.x;
    int r = tid >> 6, t = tid & 63;                 // r in {0,1}
    int blk = blockIdx.x;
    int p = blk & 3;                                // batch pair 0..3
    int g = blk >> 2;                               // 0..127
    int rp = (g << 1) + r;                          // compact row 0..255
    int y = (rp < 128) ? rp : (rp + 256);
    int iy = (y < 128) ? (y + 128) : (y - 384);
    float ay = apod(iy);
    const float* irow0 = image + ((size_t)((2 * p)     * NSZ + iy)) * NSZ;
    const float* irow1 = image + ((size_t)((2 * p + 1) * NSZ + iy)) * NSZ;

    float2 y8[8];
    {
        int ix0 = t + 128, ix1 = t + 192, ix6 = t, ix7 = t + 64;
        float w0 = ay * apod(ix0), w1 = ay * apod(ix1);
        float w6 = ay * apod(ix6), w7 = ay * apod(ix7);
        float2 x0 = make_float2(irow0[ix0] * w0, irow1[ix0] * w0);
        float2 x1 = make_float2(irow0[ix1] * w1, irow1[ix1] * w1);
        float2 x6 = make_float2(irow0[ix6] * w6, irow1[ix6] * w6);
        float2 x7 = make_float2(irow0[ix7] * w7, irow1[ix7] * w7);
        dft8_pruned(x0, x1, x6, x7, y8);
        twiddle8<0>(t, y8);
    }
    float2* A  = sm[0][r];
    float2* Bf = sm[1][r];
    #pragma unroll
    for (int q = 0; q < 8; ++q) A[PADIDX((t << 3) + q)] = y8[q];
    __syncthreads();
    {
        float2 x[8];
        #pragma unroll
        for (int pp = 0; pp < 8; ++pp) x[pp] = A[PADIDX(t + (pp << 6))];
        dft8(x, y8);
        twiddle8<1>(t, y8);
        int j = t >> 3, k = t & 7, base = k + (j << 6);
        #pragma unroll
        for (int q = 0; q < 8; ++q) Bf[PADIDX(base + (q << 3))] = y8[q];
    }
    __syncthreads();
    {
        float2 x[8];
        #pragma unroll
        for (int pp = 0; pp < 8; ++pp) x[pp] = Bf[PADIDX(t + (pp << 6))];
        dft8(x, y8);
        float2* Trow = T + (((size_t)(p << 8) + rp) << 9);
        #pragma unroll
        for (int q = 0; q < 8; ++q) Trow[t + (q << 6)] = y8[q];
    }
}

// ---------------------------------------------------------------- pass 2
// Batch-pair packed column FFT + Hermitian unpack (r9, verified).
__global__ __launch_bounds__(256) void pass2_colfft(const float2* __restrict__ T,
                                                    float2* __restrict__ kgrid) {
    __shared__ float2 B[8][578];
    int tid = threadIdx.x;
    int blk = blockIdx.x;
    int p = blk & 3;                                // batch pair
    int g = blk >> 2;                               // 0..63 col group
    const float2* Tb = T + ((size_t)p << 17);       // 256*512 per pair
    float2* Kb0 = kgrid + ((size_t)(2 * p) << 18);
    float2* Kb1 = Kb0 + ((size_t)1 << 18);

    #define COLG(c) ((g > 0) ? (((c) < 4) ? ((g << 2) + (c)) : (505 - (g << 2) + (c))) \
                             : (((c) < 4) ? (c) : (((c) == 7) ? 256 : (505 + (c)))))

    {
        int c = tid & 7, r0 = tid >> 3;             // r0 0..31
        int colg = COLG(c);
        #pragma unroll
        for (int k = 0; k < 8; ++k) {
            int rr = r0 + (k << 5);
            B[c][PADIDX(rr)] = Tb[((size_t)rr << 9) + colg];
        }
    }
    __syncthreads();
    int t = tid & 63;
    int c0 = tid >> 6;                              // slots c0 and c0+4
    float2* Ba = B[c0];
    float2* Bb = B[c0 + 4];
    float2 ya[8], yb[8];
    {
        float2 a0 = Ba[PADIDX(t)],       a1 = Ba[PADIDX(t + 64)];
        float2 a6 = Ba[PADIDX(t + 128)], a7 = Ba[PADIDX(t + 192)];
        float2 b0 = Bb[PADIDX(t)],       b1 = Bb[PADIDX(t + 64)];
        float2 b6 = Bb[PADIDX(t + 128)], b7 = Bb[PADIDX(t + 192)];
        dft8_pruned(a0, a1, a6, a7, ya); twiddle8<0>(t, ya);
        dft8_pruned(b0, b1, b6, b7, yb); twiddle8<0>(t, yb);
    }
    __syncthreads();
    #pragma unroll
    for (int q = 0; q < 8; ++q) {
        Ba[PADIDX((t << 3) + q)] = ya[q];
        Bb[PADIDX((t << 3) + q)] = yb[q];
    }
    __syncthreads();
    {
        float2 xa[8], xb[8];
        #pragma unroll
        for (int pp = 0; pp < 8; ++pp) { xa[pp] = Ba[PADIDX(t + (pp << 6))]; xb[pp] = Bb[PADIDX(t + (pp << 6))]; }
        dft8(xa, ya); twiddle8<1>(t, ya);
        dft8(xb, yb); twiddle8<1>(t, yb);
    }
    __syncthreads();
    {
        int j = t >> 3, k = t & 7, base = k + (j << 6);
        #pragma unroll
        for (int q = 0; q < 8; ++q) {
            Ba[PADIDX(base + (q << 3))] = ya[q];
            Bb[PADIDX(base + (q << 3))] = yb[q];
        }
    }
    __syncthreads();
    {
        float2 xa[8], xb[8];
        #pragma unroll
        for (int pp = 0; pp < 8; ++pp) { xa[pp] = Ba[PADIDX(t + (pp << 6))]; xb[pp] = Bb[PADIDX(t + (pp << 6))]; }
        dft8(xa, ya);
        dft8(xb, yb);
    }
    __syncthreads();
    #pragma unroll
    for (int q = 0; q < 8; ++q) {
        Ba[PADIDX(t + (q << 6))] = ya[q];
        Bb[PADIDX(t + (q << 6))] = yb[q];
    }
    __syncthreads();
    {
        int c = tid & 7, r0 = tid >> 3;
        int colg = COLG(c);
        int mc = 7 - c;
        if (g == 0) { if (c == 0) mc = 0; else if (c == 7) mc = 7; }
        #pragma unroll
        for (int k = 0; k < 16; ++k) {
            int rr = r0 + (k << 5);
            int mr = (512 - rr) & 511;
            float2 Z = B[c][PADIDX(rr)];
            float2 M = B[mc][PADIDX(mr)];
            float2 K0 = make_float2(0.5f * (Z.x + M.x), 0.5f * (Z.y - M.y));
            float2 K1 = make_float2(0.5f * (Z.y + M.y), 0.5f * (M.x - Z.x));
            size_t off = ((size_t)rr << 9) + colg;
            Kb0[off] = K0;
            Kb1[off] = K1;
        }
    }
    #undef COLG
}

// ---------------------------------------------------------------- pass 3
// Quad-cooperative KB gather, LATENCY-SCHEDULED: all 6 grid loads issue
// FIRST (independent of weights), then the 12-transcendental weight math +
// next-iteration ktraj/dcf prefetch execute under the loads' L2 latency,
// then the fma chain consumes. 4 lanes/point, DPP-only cross-lane.
__global__ __launch_bounds__(256) void interp_kb(const float* __restrict__ ktraj,
                                                 const float* __restrict__ dcf,
                                                 const float2* __restrict__ kgrid,
                                                 float* __restrict__ out) {
    int tid = threadIdx.x;
    int blk = blockIdx.x;
    int b = blk & 7;                          // XCD affinity
    int gb = blk >> 3;                        // 0..255
    int j = tid & 3;                          // lane within quad
    int q = tid >> 2;                         // quad in block 0..63

    const float SCALE = (float)GSZ / (2.0f * PI_F);
    const float2* Kb = kgrid + ((size_t)b << 18);
    const float* kt1 = ktraj + ((size_t)(b * 2)) * MPTS;
    const float* kt2 = kt1 + MPTS;
    const float* dcfb = dcf + ((size_t)b << 17);
    float* out_re = out + ((size_t)b << 17);
    float* out_im = out_re + (size_t)NBATCH * MPTS;

    int m0 = (gb << 9) + q;                   // block covers 512 points
    // preload iteration 0's point data
    float tm1 = kt1[m0] * SCALE;
    float tm2 = kt2[m0] * SCALE;
    float dd  = dcfb[m0];

    #pragma unroll 2
    for (int it = 0; it < 8; ++it) {
        int m = m0 + (it << 6);
        float f1 = floorf(tm1), f2 = floorf(tm2);
        int if1 = (int)f1, if2 = (int)f2;
        int e0 = (if2 - 2) & ~1;              // even base col
        int cpair = (e0 + 2 * j) & 511;       // even → pair never wraps mid

        // ---- issue all 6 row loads first (only depend on indices)
        F4 v[6];
        #pragma unroll
        for (int a = 0; a < 6; ++a) {
            int rowb = (if1 + a - 2) & 511;
            v[a] = *reinterpret_cast<const F4*>(Kb + ((size_t)rowb << 9) + cpair);
        }

        // ---- weight math executes under the loads' latency
        float u2 = tm2 - (float)(e0 + 2 * j);
        float w2a = kbw(u2);
        float w2b = kbw(u2 - 1.0f);
        float fr1 = tm1 - f1;
        float w1A = kbw(fr1 - (float)(j - 2));
        float w1B = kbw(fr1 - (float)(j + 2));
        float w1_[6];
        w1_[0] = qdpp<0x00>(w1A);
        w1_[1] = qdpp<0x55>(w1A);
        w1_[2] = qdpp<0xAA>(w1A);
        w1_[3] = qdpp<0xFF>(w1A);
        w1_[4] = qdpp<0x00>(w1B);
        w1_[5] = qdpp<0x55>(w1B);
        float myd = dd;

        // ---- prefetch next iteration's point data (also under latency)
        if (it < 7) {
            int mn = m + 64;
            tm1 = kt1[mn] * SCALE;
            tm2 = kt2[mn] * SCALE;
            dd  = dcfb[mn];
        }

        // ---- consume
        float c0re = 0.f, c0im = 0.f, c1re = 0.f, c1im = 0.f;
        #pragma unroll
        for (int a = 0; a < 6; ++a) {
            c0re = fmaf(w1_[a], v[a].x, c0re); c0im = fmaf(w1_[a], v[a].y, c0im);
            c1re = fmaf(w1_[a], v[a].z, c1re); c1im = fmaf(w1_[a], v[a].w, c1im);
        }
        float p_re = fmaf(w2a, c0re, w2b * c1re);
        float p_im = fmaf(w2a, c0im, w2b * c1im);
        p_re += qdpp<0xB1>(p_re);  p_re += qdpp<0x4E>(p_re);
        p_im += qdpp<0xB1>(p_im);  p_im += qdpp<0x4E>(p_im);

        if (j == 0) out_re[m] = p_re * myd;
        if (j == 1) out_im[m] = p_im * myd;
    }
}

// ---------------------------------------------------------------- launch

extern "C" void kernel_launch(void* const* d_in, const int* in_sizes, int n_in,
                              void* d_out, int out_size, void* d_ws, size_t ws_size,
                              hipStream_t stream) {
    const float* image = (const float*)d_in[0];   // (8,256,256) f32
    const float* ktraj = (const float*)d_in[1];   // (8,2,131072) f32
    const float* dcf   = (const float*)d_in[2];   // (8,131072) f32
    float* out = (float*)d_out;                   // (2,8,131072) f32

    float2* T     = (float2*)d_ws;                        // 4 pairs *256*512 c64 = 4.2 MB
    float2* kgrid = T + (size_t)4 * 256 * GSZ;            // 8*512*512 c64 = 16.8 MB

    pass1_rowfft<<<512, 128, 0, stream>>>(image, T);      // 4 pairs * 256 rows / 2 per block
    pass2_colfft<<<256, 256, 0, stream>>>(T, kgrid);      // 4 pairs * 512 cols / 8 per block
    interp_kb<<<NBATCH * 256, 256, 0, stream>>>(ktraj, dcf, kgrid, out);
}